// Round 4
// baseline (149.943 us; speedup 1.0000x reference)
//
#include <hip/hip_runtime.h>
#include <cmath>

#define NWALK 4096
#define NXD   48
#define HID   256
#define GCONST 0.7978845608028654f

typedef _Float16 half8   __attribute__((ext_vector_type(8)));
typedef float    float4v __attribute__((ext_vector_type(4)));

// ---------- prep_w: W2c[j*256+i] = fp16(W2[i*256+j]) (tiled transpose) + W1 fp16 cast
__global__ __launch_bounds__(256) void prep_w(const float* __restrict__ W2,
                                              const float* __restrict__ W1,
                                              _Float16* __restrict__ W2c,
                                              _Float16* __restrict__ W1c) {
    __shared__ float tile[64][65];
    const int bi = blockIdx.x;          // i-tile
    const int bj = blockIdx.y;          // j-tile
    const int tx = threadIdx.x & 63;
    const int ty = threadIdx.x >> 6;    // 0..3
    #pragma unroll
    for (int r = 0; r < 16; ++r) {
        int il = ty * 16 + r;
        tile[tx][il] = W2[(bi * 64 + il) * HID + bj * 64 + tx];
    }
    __syncthreads();
    #pragma unroll
    for (int r = 0; r < 16; ++r) {
        int jl = ty * 16 + r;
        W2c[(bj * 64 + jl) * HID + bi * 64 + tx] = (_Float16)tile[jl][tx];
    }
    // W1 cast: 48 rows split over the 16 blocks (3 rows each)
    const int b = blockIdx.y * 4 + blockIdx.x;
    #pragma unroll
    for (int r = 0; r < 3; ++r) {
        int k = b * 3 + r;
        W1c[k * HID + threadIdx.x] = (_Float16)W1[k * HID + threadIdx.x];
    }
}

// ---------- prep_h: per-walker layer 1 -> t1h, h1h, ch (fp16), 16 walkers/block
__global__ __launch_bounds__(256) void prep_h(const float* __restrict__ x,
                                              const float* __restrict__ W1,
                                              const float* __restrict__ b1,
                                              _Float16* __restrict__ t1h,
                                              _Float16* __restrict__ h1h,
                                              _Float16* __restrict__ ch) {
    __shared__ float xs[16][NXD];
    const int i  = threadIdx.x;
    const int w0 = blockIdx.x * 16;

    float col[NXD];
    float S = 0.f;
    #pragma unroll
    for (int k = 0; k < NXD; ++k) {
        float v = W1[k * HID + i];          // coalesced across i
        col[k] = v;
        S = fmaf(v, v, S);
    }
    #pragma unroll
    for (int t = threadIdx.x; t < 16 * NXD; t += 256)
        ((float*)xs)[t] = x[w0 * NXD + t];
    __syncthreads();

    const float b = b1[i];
    #pragma unroll 4
    for (int w = 0; w < 16; ++w) {
        float a1 = b;
        #pragma unroll
        for (int k = 0; k < NXD; ++k)
            a1 = fmaf(xs[w][k], col[k], a1);   // xs broadcast
        float h1 = tanhf(a1);
        float t1 = 1.f - h1 * h1;
        int off = (w0 + w) * HID + i;
        t1h[off] = (_Float16)t1;
        h1h[off] = (_Float16)h1;
        ch[off]  = (_Float16)(S * h1 * t1);
    }
}

// ---------- eloc: lean staging + MFMA + epilogue
__global__ __launch_bounds__(256, 4) void eloc_kernel(
    const float* __restrict__ x,
    const float* __restrict__ b2,
    const float* __restrict__ w3,
    const _Float16* __restrict__ W2c,
    const _Float16* __restrict__ W1c,
    const _Float16* __restrict__ t1h,
    const _Float16* __restrict__ h1h,
    const _Float16* __restrict__ ch,
    float* __restrict__ out)
{
    // AsT rows 0..47: t1_i*W1[k,i] (16B-chunk XOR swizzle); row 48: h1; row 49: c
    __shared__ __align__(16) _Float16 AsT[50 * HID];   // 25.6 KB
    __shared__ float xs[NXD];
    __shared__ float b2s[HID], w3s[HID];
    __shared__ float us[HID], uh2s[HID], ps[HID];
    __shared__ float gw[4][NXD];
    __shared__ float wred[4][2];
    __shared__ float ggpot[2];

    const int w    = blockIdx.x;
    const int tid  = threadIdx.x;
    const int wave = tid >> 6;
    const int lane = tid & 63;
    const int n16  = lane & 15;
    const int quad = lane >> 4;

    // ---- staging: AsT[k][chunk ci^(k&7)] = t1[ci-chunk] * W1c[k][ci-chunk] ----
    {
        const int ci    = tid & 31;   // i-chunk (8 halfs)
        const int krow0 = tid >> 5;   // 0..7
        half8 th = *(const half8*)(t1h + w * HID + ci * 8);
        #pragma unroll
        for (int s = 0; s < 6; ++s) {
            int k = s * 8 + krow0;
            half8 wv = *(const half8*)(W1c + k * HID + ci * 8);
            *(half8*)(AsT + k * HID + ((ci ^ (k & 7)) * 8)) = wv * th;
        }
        if (tid < 32) {
            half8 hv = *(const half8*)(h1h + w * HID + tid * 8);
            *(half8*)(AsT + 48 * HID + tid * 8) = hv;                    // 48&7=0
        } else if (tid < 64) {
            int c2 = tid - 32;
            half8 cv = *(const half8*)(ch + w * HID + c2 * 8);
            *(half8*)(AsT + 49 * HID + ((c2 ^ 1) * 8)) = cv;             // 49&7=1
        }
        if (tid < NXD) xs[tid] = x[w * NXD + tid];
        b2s[tid] = b2[tid];
        w3s[tid] = w3[tid];
    }
    __syncthreads();

    // ---- MFMA: Mt[j,k] = sum_i W2[i,j]*As[i,k]; kt=3 gives a2 (col0), p (col1) ----
    float4v acc[4][4];
    #pragma unroll
    for (int a = 0; a < 4; ++a)
        #pragma unroll
        for (int kt = 0; kt < 4; ++kt)
            acc[a][kt] = (float4v){0.f, 0.f, 0.f, 0.f};

    #pragma unroll
    for (int step = 0; step < 8; ++step) {
        const int i0 = step * 32 + quad * 8;
        half8 af[4];
        #pragma unroll
        for (int a = 0; a < 4; ++a) {
            int j = (wave * 4 + a) * 16 + n16;          // A[m=n16][kk=quad*8+t]
            af[a] = *(const half8*)(W2c + j * HID + i0);
        }
        half8 bf[4];
        #pragma unroll
        for (int kt = 0; kt < 4; ++kt) {
            int krow = (kt < 3) ? (kt * 16 + n16) : (48 + (n16 & 1));
            int goff = krow * HID + ((((step * 4 + quad) ^ (krow & 7)) << 3));
            bf[kt] = *(const half8*)(AsT + goff);       // B[kk][n=n16]
        }
        #pragma unroll
        for (int a = 0; a < 4; ++a)
            #pragma unroll
            for (int kt = 0; kt < 4; ++kt)
                acc[a][kt] = __builtin_amdgcn_mfma_f32_16x16x32_f16(
                    af[a], bf[kt], acc[a][kt], 0, 0, 0);
    }

    // ---- activations from kt=3 accumulator columns 0 (a2) and 1 (p) ----
    if (n16 == 0) {
        #pragma unroll
        for (int a = 0; a < 4; ++a)
            #pragma unroll
            for (int reg = 0; reg < 4; ++reg) {
                int j = (wave * 4 + a) * 16 + quad * 4 + reg;
                float a2 = acc[a][3][reg] + b2s[j];
                float h2 = tanhf(a2);
                float t2 = 1.f - h2 * h2;
                float u  = w3s[j] * t2;
                us[j]   = u;
                uh2s[j] = u * h2;
            }
    } else if (n16 == 1) {
        #pragma unroll
        for (int a = 0; a < 4; ++a)
            #pragma unroll
            for (int reg = 0; reg < 4; ++reg) {
                int j = (wave * 4 + a) * 16 + quad * 4 + reg;
                ps[j] = acc[a][3][reg];
            }
    }
    __syncthreads();

    // ---- T1 = sum_j u h2 Q_j ; g_k = sum_j Mt[j,k] u_j ; T2 = sum_j u_j p_j ----
    float t1p = 0.f;
    float gp[3] = {0.f, 0.f, 0.f};
    #pragma unroll
    for (int a = 0; a < 4; ++a) {
        #pragma unroll
        for (int reg = 0; reg < 4; ++reg) {
            int j = (wave * 4 + a) * 16 + quad * 4 + reg;
            float uh2 = uh2s[j];
            float uu  = us[j];
            #pragma unroll
            for (int kt = 0; kt < 3; ++kt) {
                float m = acc[a][kt][reg];
                t1p    = fmaf(m * m, uh2, t1p);
                gp[kt] = fmaf(m, uu, gp[kt]);
            }
        }
    }
    float rt1 = t1p;
    float rt2 = us[tid] * ps[tid];
    #pragma unroll
    for (int off = 32; off > 0; off >>= 1) {
        rt1 += __shfl_down(rt1, off, 64);
        rt2 += __shfl_down(rt2, off, 64);
    }
    #pragma unroll
    for (int kt = 0; kt < 3; ++kt) {
        gp[kt] += __shfl_xor(gp[kt], 16, 64);
        gp[kt] += __shfl_xor(gp[kt], 32, 64);
    }
    if (lane == 0) { wred[wave][0] = rt1; wred[wave][1] = rt2; }
    if (lane < 16) {
        #pragma unroll
        for (int kt = 0; kt < 3; ++kt) gw[wave][kt * 16 + lane] = gp[kt];
    }
    __syncthreads();

    float ggp = 0.f, potp = 0.f;
    if (tid < NXD) {
        float g = gw[0][tid] + gw[1][tid] + gw[2][tid] + gw[3][tid];
        ggp  = g * g;
        potp = 0.5f * xs[tid] * xs[tid];
    }
    if (wave == 0) {
        #pragma unroll
        for (int off = 32; off > 0; off >>= 1) {
            ggp  += __shfl_down(ggp, off, 64);
            potp += __shfl_down(potp, off, 64);
        }
        if (lane == 0) { ggpot[0] = ggp; ggpot[1] = potp; }
    }
    __syncthreads();

    if (tid == 0) {
        float T1 = wred[0][0] + wred[1][0] + wred[2][0] + wred[3][0];
        float T2 = wred[0][1] + wred[1][1] + wred[2][1] + wred[3][1];
        float GG = ggpot[0], PT = ggpot[1];
        float kin = T1 + T2 - 0.5f * GG;

        float d01 = (xs[0]-xs[1])*(xs[0]-xs[1]) + (xs[2]-xs[1])*(xs[2]-xs[1]);
        float d02 = (xs[0]-xs[2])*(xs[0]-xs[2]) + (xs[1]-xs[2])*(xs[1]-xs[2]);
        float d12 = (xs[3]-xs[5])*(xs[3]-xs[5]) + (xs[4]-xs[5])*(xs[4]-xs[5]);
        float inter = GCONST * (expf(-2.f*d01) + expf(-2.f*d02) + expf(-2.f*d12));

        out[w]             = kin + PT + inter;
        out[NWALK + w]     = kin;
        out[2 * NWALK + w] = PT;
        out[3 * NWALK + w] = inter;
    }
}

extern "C" void kernel_launch(void* const* d_in, const int* in_sizes, int n_in,
                              void* d_out, int out_size, void* d_ws, size_t ws_size,
                              hipStream_t stream) {
    const float* x  = (const float*)d_in[0];
    const float* W1 = (const float*)d_in[1];
    const float* b1 = (const float*)d_in[2];
    const float* W2 = (const float*)d_in[3];
    const float* b2 = (const float*)d_in[4];
    const float* w3 = (const float*)d_in[5];
    float* out = (float*)d_out;

    char* ws = (char*)d_ws;
    _Float16* W2c = (_Float16*)(ws);                       // 128 KB
    _Float16* W1c = (_Float16*)(ws + 131072);              // 24 KB
    _Float16* t1h = (_Float16*)(ws + 155648);              // 2 MB
    _Float16* h1h = (_Float16*)(ws + 2252800);             // 2 MB
    _Float16* chv = (_Float16*)(ws + 4349952);             // 2 MB (ends 6.15 MB)

    prep_w<<<dim3(4, 4), 256, 0, stream>>>(W2, W1, W2c, W1c);
    prep_h<<<NWALK / 16, 256, 0, stream>>>(x, W1, b1, t1h, h1h, chv);
    eloc_kernel<<<NWALK, 256, 0, stream>>>(x, b2, w3, W2c, W1c, t1h, h1h, chv, out);
}